// Round 7
// baseline (174.663 us; speedup 1.0000x reference)
//
#include <hip/hip_runtime.h>
#include <math.h>

#define BATCH 2048
#define SEQ 512
#define DIM 128

typedef float fx4 __attribute__((ext_vector_type(4)));

// DPP rotate-within-16 add: after ror 1,2,4,8 every lane holds its 16-group sum.
template<int CTRL>
__device__ __forceinline__ float dpp_add(float x) {
    int y = __builtin_amdgcn_update_dpp(0, __float_as_int(x), CTRL, 0xf, 0xf, true);
    return x + __int_as_float(y);
}

// Single fused kernel: per-block prep (qk/qp/c0 -> LDS; Wk is L2/L3-hot after
// the first blocks, so the re-read costs ~0 HBM), then streaming online softmax.
__global__ __launch_bounds__(256, 8) void ap_fused(
    const float* __restrict__ x, const float* __restrict__ pos,
    const int* __restrict__ mask, const float* __restrict__ query,
    const float* __restrict__ Wk, const float* __restrict__ bk,
    const float* __restrict__ Wv, const float* __restrict__ bv,
    const float* __restrict__ Wp, const float* __restrict__ bp,
    float* __restrict__ out)
{
    __shared__ alignas(16) float sqk[136];   // [0..127] qk, [128..131] qp, [132] c0
    __shared__ float spos[SEQ];
    __shared__ float sacc[16][132];          // +4 pad rows
    __shared__ float sm[16], sl[16];
    __shared__ alignas(16) float t[DIM];
    __shared__ float ppart[128];
    __shared__ float pq[128][4];
    __shared__ float pc[128];

    const int b   = blockIdx.x;
    const int tid = threadIdx.x;
    const int w   = tid >> 6;              // wave 0..3, owns rows [128w, 128w+128)
    const int g   = (tid >> 4) & 3;        // 16-lane group: row g of each 4-row step
    const int ln  = tid & 15;              // lane: owns floats [4ln,4ln+4) and [64+4ln,..)
    const int sid = tid >> 4;              // softmax state 0..15

    const fx4* xw = (const fx4*)(x + (size_t)b * SEQ * DIM) + w * 4096;
    const int rb = g * 32 + ln;

#define LD(i, VA, VB)                                             \
    {                                                             \
        VA = xw[(((i) & 31) * 128 + rb)];                         \
        VB = xw[(((i) & 31) * 128 + rb + 16)];                    \
    }

    // 1) x prefetch first — 8 loads in flight per lane through the whole prologue
    fx4 vA0, vB0, vA1, vB1, vA2, vB2, vA3, vB3;
    LD(0, vA0, vB0); LD(1, vA1, vB1); LD(2, vA2, vB2); LD(3, vA3, vB3);

    // 2) pos/mask early loads, held in registers across the prep phase
    const float4* pos4 = (const float4*)pos + (size_t)b * SEQ;
    float4 p4a = pos4[tid];
    float4 p4b = pos4[tid + 256];
    int mka = mask[(size_t)b * SEQ + tid];
    int mkb = mask[(size_t)b * SEQ + tid + 256];

    // 3) fused prep: qk = SCALE*log2e * Wk^T q ; qp = ... Wp^T q ; c0 = q.(bk+bp)
    const float S2 = 0.08838834764831845f * 1.4426950408889634f;  // 128^-0.5 * log2(e)
    const int d = tid & 127, hk = tid >> 7;   // 2 threads per output d, k-split
    {
        float acc = 0.f;
        const int k0 = hk * 64;
        #pragma unroll 16
        for (int k = 0; k < 64; ++k) acc += query[k0 + k] * Wk[(k0 + k) * 128 + d];
        if (hk) ppart[d] = acc;
        if (tid < 128) {
            float q = query[tid];
            float4 wp = ((const float4*)Wp)[tid];
            pq[tid][0] = q * wp.x; pq[tid][1] = q * wp.y;
            pq[tid][2] = q * wp.z; pq[tid][3] = q * wp.w;
            pc[tid] = q * (bk[tid] + bp[tid]);
        }
        __syncthreads();
        if (!hk) {
            sqk[d] = (acc + ppart[d]) * S2;
        } else if (d < 4) {
            float s = 0.f;
            #pragma unroll
            for (int k = 0; k < 128; ++k) s += pq[k][d];
            sqk[128 + d] = s * S2;
        } else if (d == 4) {
            float s = 0.f;
            #pragma unroll
            for (int k = 0; k < 128; ++k) s += pc[k];
            sqk[132] = s * S2;
        }
        __syncthreads();
    }

    // 4) positional scores from the held registers
    {
        const float qp0 = sqk[128], qp1 = sqk[129], qp2 = sqk[130], qp3 = sqk[131];
        const float c0  = sqk[132];
        float sa = fmaf(qp0, p4a.x, fmaf(qp1, p4a.y, fmaf(qp2, p4a.z, fmaf(qp3, p4a.w, c0))));
        if (mka == 0) sa = -1e30f;
        spos[tid] = sa;
        float sb = fmaf(qp0, p4b.x, fmaf(qp1, p4b.y, fmaf(qp2, p4b.z, fmaf(qp3, p4b.w, c0))));
        if (mkb == 0) sb = -1e30f;
        spos[tid + 256] = sb;
    }
    const float4 qkA = *(const float4*)&sqk[4 * ln];
    const float4 qkB = *(const float4*)&sqk[64 + 4 * ln];
    __syncthreads();

    const int sp0 = w * 128 + g;           // spos index of this group's row at step 0

    float m = -INFINITY, den = 0.f;
    fx4 aA = {0.f, 0.f, 0.f, 0.f}, aB = {0.f, 0.f, 0.f, 0.f};

#define PROC(VA, VB, J)                                                       \
    {                                                                         \
        float r = (VA).x * qkA.x;                                             \
        r = fmaf((VA).y, qkA.y, r);                                           \
        r = fmaf((VA).z, qkA.z, r);                                           \
        r = fmaf((VA).w, qkA.w, r);                                           \
        r = fmaf((VB).x, qkB.x, r);                                           \
        r = fmaf((VB).y, qkB.y, r);                                           \
        r = fmaf((VB).z, qkB.z, r);                                           \
        r = fmaf((VB).w, qkB.w, r);                                           \
        r = dpp_add<0x121>(r);                                                \
        r = dpp_add<0x122>(r);                                                \
        r = dpp_add<0x124>(r);                                                \
        r = dpp_add<0x128>(r);                                                \
        float sc = r + spos[sp0 + 4 * (J)];                                   \
        float dd = sc - m;                                                    \
        if (__builtin_expect(dd > 8.0f, 0)) {                                 \
            float f = __builtin_amdgcn_exp2f(-dd);                            \
            den = fmaf(den, f, 1.0f);                                         \
            aA.x = fmaf(aA.x, f, (VA).x); aA.y = fmaf(aA.y, f, (VA).y);       \
            aA.z = fmaf(aA.z, f, (VA).z); aA.w = fmaf(aA.w, f, (VA).w);       \
            aB.x = fmaf(aB.x, f, (VB).x); aB.y = fmaf(aB.y, f, (VB).y);       \
            aB.z = fmaf(aB.z, f, (VB).z); aB.w = fmaf(aB.w, f, (VB).w);       \
            m = sc;                                                           \
        } else {                                                              \
            float p = __builtin_amdgcn_exp2f(dd);                             \
            den += p;                                                         \
            aA.x = fmaf(p, (VA).x, aA.x); aA.y = fmaf(p, (VA).y, aA.y);       \
            aA.z = fmaf(p, (VA).z, aA.z); aA.w = fmaf(p, (VA).w, aA.w);       \
            aB.x = fmaf(p, (VB).x, aB.x); aB.y = fmaf(p, (VB).y, aB.y);       \
            aB.z = fmaf(p, (VB).z, aB.z); aB.w = fmaf(p, (VB).w, aB.w);       \
        }                                                                     \
    }

    // ---- 4-deep rotating pipeline over 8 chunks (32 steps × 4 rows) ----
    #pragma unroll
    for (int ch = 0; ch < 8; ++ch) {
        const int base = 4 * ch;
        PROC(vA0, vB0, base + 0); LD(base + 4, vA0, vB0);
        PROC(vA1, vB1, base + 1); LD(base + 5, vA1, vB1);
        PROC(vA2, vB2, base + 2); LD(base + 6, vA2, vB2);
        PROC(vA3, vB3, base + 3); LD(base + 7, vA3, vB3);
    }
#undef PROC
#undef LD

    // ---- merge the 16 states ----
    if (ln == 0) { sm[sid] = m; sl[sid] = den; }
    __syncthreads();
    float gm = -INFINITY;
    #pragma unroll
    for (int k = 0; k < 16; ++k) gm = fmaxf(gm, sm[k]);
    float f = __builtin_amdgcn_exp2f(m - gm);
    sacc[sid][4 * ln + 0]      = aA.x * f;
    sacc[sid][4 * ln + 1]      = aA.y * f;
    sacc[sid][4 * ln + 2]      = aA.z * f;
    sacc[sid][4 * ln + 3]      = aA.w * f;
    sacc[sid][64 + 4 * ln + 0] = aB.x * f;
    sacc[sid][64 + 4 * ln + 1] = aB.y * f;
    sacc[sid][64 + 4 * ln + 2] = aB.z * f;
    sacc[sid][64 + 4 * ln + 3] = aB.w * f;
    float gl = 0.f;
    #pragma unroll
    for (int k = 0; k < 16; ++k) gl += sl[k] * __builtin_amdgcn_exp2f(sm[k] - gm);
    __syncthreads();

    if (tid < DIM) {
        float s0 = 0.f;
        #pragma unroll
        for (int k = 0; k < 16; ++k) s0 += sacc[k][tid];
        t[tid] = s0;
    }
    __syncthreads();

    // ---- epilogue: pooled[b,k] = bv[k] + (Wv[k,:] . t) / gl ----
    if (tid < DIM) {
        const float4* wv4 = (const float4*)(Wv + tid * DIM);
        const float4* t4  = (const float4*)t;
        float sum = 0.f;
        #pragma unroll
        for (int j = 0; j < 32; ++j) {
            float4 wv = wv4[j];
            float4 tv = t4[j];
            sum += wv.x * tv.x + wv.y * tv.y + wv.z * tv.z + wv.w * tv.w;
        }
        out[(size_t)b * DIM + tid] = bv[tid] + sum / gl;
    }
}

extern "C" void kernel_launch(void* const* d_in, const int* in_sizes, int n_in,
                              void* d_out, int out_size, void* d_ws, size_t ws_size,
                              hipStream_t stream) {
    const float* x     = (const float*)d_in[0];
    const float* pos   = (const float*)d_in[1];
    const int*   mask  = (const int*)d_in[2];     // bool -> int32 per harness convention
    const float* query = (const float*)d_in[3];
    const float* Wk    = (const float*)d_in[4];
    const float* bk    = (const float*)d_in[5];
    const float* Wv    = (const float*)d_in[6];
    const float* bv    = (const float*)d_in[7];
    const float* Wp    = (const float*)d_in[8];
    const float* bp    = (const float*)d_in[9];
    float* out = (float*)d_out;

    ap_fused<<<BATCH, 256, 0, stream>>>(x, pos, mask, query, Wk, bk, Wv, bv, Wp, bp, out);
}

// Round 9
// 118.028 us; speedup vs baseline: 1.4798x; 1.4798x over previous
//
#include <hip/hip_runtime.h>
#include <math.h>

#define BATCH 2048
#define SEQ 512
#define DIM 128

// DPP rotate-within-16 add: after ror 1,2,4,8 every lane holds its 16-group sum.
template<int CTRL>
__device__ __forceinline__ float dpp_add(float x) {
    int y = __builtin_amdgcn_update_dpp(0, __float_as_int(x), CTRL, 0xf, 0xf, true);
    return x + __int_as_float(y);
}

// ws layout: [0..127] qk (SCALE*log2e), [128..131] qp, [132] c0 — exp2-prescaled
__global__ __launch_bounds__(256) void ap_prep(
    const float* __restrict__ query,
    const float* __restrict__ Wk, const float* __restrict__ bk,
    const float* __restrict__ Wp, const float* __restrict__ bp,
    float* __restrict__ ws)
{
    __shared__ float part[128];
    __shared__ float pq[128][4];
    __shared__ float pc[128];
    const float S2 = 0.08838834764831845f * 1.4426950408889634f;  // 128^-0.5 * log2(e)
    const int t = threadIdx.x;
    const int d = t & 127, hk = t >> 7;   // 2 threads per output d, k-split
    float acc = 0.f;
    const int k0 = hk * 64;
    #pragma unroll 16
    for (int k = 0; k < 64; ++k) acc += query[k0 + k] * Wk[(k0 + k) * 128 + d];
    if (hk) part[d] = acc;
    if (t < 128) {
        float q = query[t];
        float4 wp = ((const float4*)Wp)[t];
        pq[t][0] = q * wp.x; pq[t][1] = q * wp.y;
        pq[t][2] = q * wp.z; pq[t][3] = q * wp.w;
        pc[t] = q * (bk[t] + bp[t]);
    }
    __syncthreads();
    if (!hk) {
        ws[d] = (acc + part[d]) * S2;
    } else if (d < 4) {
        float s = 0.f;
        #pragma unroll
        for (int k = 0; k < 128; ++k) s += pq[k][d];
        ws[128 + d] = s * S2;
    } else if (d == 4) {
        float s = 0.f;
        #pragma unroll
        for (int k = 0; k < 128; ++k) s += pc[k];
        ws[132] = s * S2;
    }
}

__global__ __launch_bounds__(256, 8) void ap_main(
    const float* __restrict__ x, const float* __restrict__ pos,
    const int* __restrict__ mask,
    const float* __restrict__ Wv, const float* __restrict__ bv,
    const float* __restrict__ ws, float* __restrict__ out)
{
    __shared__ float spos[520];                    // padded: idx = s + (s>>7)
    __shared__ float sacc[8][DIM];
    __shared__ float sm[8], sl[8];
    __shared__ alignas(16) float t[DIM];

    const int b   = blockIdx.x;
    const int tid = threadIdx.x;
    const int l   = tid & 63;
    const int w   = tid >> 6;         // wave 0..3, owns rows [128w, 128w+128)
    const int h   = (tid >> 5) & 1;   // half: even(0)/odd(1) rows of the wave
    const int c   = tid & 31;         // column group (4 floats)
    const int st  = tid >> 5;         // merge state 0..7

    // ---- issue first 6 x-loads immediately (hide spos phase under them) ----
    const float4* xw = (const float4*)(x + (size_t)b * SEQ * DIM) + w * 4096;
    float4 v0 = xw[0 * 64 + l];
    float4 v1 = xw[1 * 64 + l];
    float4 v2 = xw[2 * 64 + l];
    float4 v3 = xw[3 * 64 + l];
    float4 v4 = xw[4 * 64 + l];
    float4 v5 = xw[5 * 64 + l];

    const float4 qk4 = ((const float4*)ws)[c];
    const float qp0 = ws[128], qp1 = ws[129], qp2 = ws[130], qp3 = ws[131];
    const float c0  = ws[132];

    // positional score (+c0), exp2-prescaled, masked; bank-conflict-padded
    #pragma unroll
    for (int s = tid; s < SEQ; s += 256) {
        float4 p4 = ((const float4*)pos)[(size_t)b * SEQ + s];
        float sc = fmaf(qp0, p4.x, fmaf(qp1, p4.y, fmaf(qp2, p4.z, fmaf(qp3, p4.w, c0))));
        if (mask[(size_t)b * SEQ + s] == 0) sc = -1e30f;
        spos[s + (s >> 7)] = sc;
    }
    __syncthreads();

    const int sp0 = w * 129 + h;      // padded spos index of row (128w + h)

    float m = -INFINITY, den = 0.f;
    float ax = 0.f, ay = 0.f, az = 0.f, aw = 0.f;

#define PROC(V, J)                                                          \
    {                                                                       \
        float r = (V).x * qk4.x;                                            \
        r = fmaf((V).y, qk4.y, r);                                          \
        r = fmaf((V).z, qk4.z, r);                                          \
        r = fmaf((V).w, qk4.w, r);                                          \
        r = dpp_add<0x121>(r);                                              \
        r = dpp_add<0x122>(r);                                              \
        r = dpp_add<0x124>(r);                                              \
        r = dpp_add<0x128>(r);                                              \
        r += __shfl_xor(r, 16);                                             \
        float sc = r + spos[sp0 + 2 * (J)];                                 \
        float dd = sc - m;                                                  \
        if (__builtin_expect(dd > 8.0f, 0)) {                               \
            float f = __builtin_amdgcn_exp2f(-dd);                          \
            den = fmaf(den, f, 1.0f);                                       \
            ax = fmaf(ax, f, (V).x); ay = fmaf(ay, f, (V).y);               \
            az = fmaf(az, f, (V).z); aw = fmaf(aw, f, (V).w);               \
            m = sc;                                                         \
        } else {                                                            \
            float p = __builtin_amdgcn_exp2f(dd);                           \
            den += p;                                                       \
            ax = fmaf(p, (V).x, ax); ay = fmaf(p, (V).y, ay);               \
            az = fmaf(p, (V).z, az); aw = fmaf(p, (V).w, aw);               \
        }                                                                   \
    }

    // ---- 6-deep rotating pipeline; exactly 64 row-pair iterations ----
    // STEP(V, J): guard both PROC (J<64) and prefetch (J+6<64) at compile time.
#define STEP(V, J)                                                          \
    if ((J) < 64) {                                                         \
        PROC(V, J);                                                         \
        if ((J) + 6 < 64) V = xw[(((J) + 6) * 64) + l];                     \
    }

    #pragma unroll
    for (int ch = 0; ch < 11; ++ch) {
        const int base = 6 * ch;      // 66 slots, guards truncate to 64
        STEP(v0, base + 0);
        STEP(v1, base + 1);
        STEP(v2, base + 2);
        STEP(v3, base + 3);
        STEP(v4, base + 4);
        STEP(v5, base + 5);
    }
#undef STEP
#undef PROC

    // ---- merge the 8 states ----
    if (c == 0) { sm[st] = m; sl[st] = den; }
    __syncthreads();
    float gm = -INFINITY;
    #pragma unroll
    for (int k = 0; k < 8; ++k) gm = fmaxf(gm, sm[k]);
    float f = __builtin_amdgcn_exp2f(m - gm);
    sacc[st][4 * c + 0] = ax * f;
    sacc[st][4 * c + 1] = ay * f;
    sacc[st][4 * c + 2] = az * f;
    sacc[st][4 * c + 3] = aw * f;
    float gl = 0.f;
    #pragma unroll
    for (int k = 0; k < 8; ++k) gl += sl[k] * __builtin_amdgcn_exp2f(sm[k] - gm);
    __syncthreads();

    if (tid < DIM) {
        float s0 = 0.f;
        #pragma unroll
        for (int k = 0; k < 8; ++k) s0 += sacc[k][tid];
        t[tid] = s0;
    }
    __syncthreads();

    // ---- epilogue: pooled[b,k] = bv[k] + (Wv[k,:] . t) / gl ----
    if (tid < DIM) {
        const float4* wv4 = (const float4*)(Wv + tid * DIM);
        const float4* t4  = (const float4*)t;
        float sum = 0.f;
        #pragma unroll
        for (int j = 0; j < 32; ++j) {
            float4 wv = wv4[j];
            float4 tv = t4[j];
            sum += wv.x * tv.x + wv.y * tv.y + wv.z * tv.z + wv.w * tv.w;
        }
        out[(size_t)b * DIM + tid] = bv[tid] + sum / gl;
    }
}

extern "C" void kernel_launch(void* const* d_in, const int* in_sizes, int n_in,
                              void* d_out, int out_size, void* d_ws, size_t ws_size,
                              hipStream_t stream) {
    const float* x     = (const float*)d_in[0];
    const float* pos   = (const float*)d_in[1];
    const int*   mask  = (const int*)d_in[2];     // bool -> int32 per harness convention
    const float* query = (const float*)d_in[3];
    const float* Wk    = (const float*)d_in[4];
    const float* bk    = (const float*)d_in[5];
    const float* Wv    = (const float*)d_in[6];
    const float* bv    = (const float*)d_in[7];
    const float* Wp    = (const float*)d_in[8];
    const float* bp    = (const float*)d_in[9];
    float* out = (float*)d_out;
    float* ws  = (float*)d_ws;

    ap_prep<<<1, 256, 0, stream>>>(query, Wk, bk, Wp, bp, ws);
    ap_main<<<BATCH, 256, 0, stream>>>(x, pos, mask, Wv, bv, ws, out);
}

// Round 10
// 117.783 us; speedup vs baseline: 1.4829x; 1.0021x over previous
//
#include <hip/hip_runtime.h>
#include <math.h>

#define BATCH 2048
#define SEQ 512
#define DIM 128

// DPP rotate-within-16 add: after ror 1,2,4,8 every lane holds its 16-group sum.
template<int CTRL>
__device__ __forceinline__ float dpp_add(float x) {
    int y = __builtin_amdgcn_update_dpp(0, __float_as_int(x), CTRL, 0xf, 0xf, true);
    return x + __int_as_float(y);
}

// ws layout: [0..127] qk (SCALE*log2e), [128..131] qp, [132] c0 — exp2-prescaled
__global__ __launch_bounds__(256) void ap_prep(
    const float* __restrict__ query,
    const float* __restrict__ Wk, const float* __restrict__ bk,
    const float* __restrict__ Wp, const float* __restrict__ bp,
    float* __restrict__ ws)
{
    __shared__ float part[128];
    __shared__ float pq[128][4];
    __shared__ float pc[128];
    const float S2 = 0.08838834764831845f * 1.4426950408889634f;  // 128^-0.5 * log2(e)
    const int t = threadIdx.x;
    const int d = t & 127, hk = t >> 7;   // 2 threads per output d, k-split
    float acc = 0.f;
    const int k0 = hk * 64;
    #pragma unroll 16
    for (int k = 0; k < 64; ++k) acc += query[k0 + k] * Wk[(k0 + k) * 128 + d];
    if (hk) part[d] = acc;
    if (t < 128) {
        float q = query[t];
        float4 wp = ((const float4*)Wp)[t];
        pq[t][0] = q * wp.x; pq[t][1] = q * wp.y;
        pq[t][2] = q * wp.z; pq[t][3] = q * wp.w;
        pc[t] = q * (bk[t] + bp[t]);
    }
    __syncthreads();
    if (!hk) {
        ws[d] = (acc + part[d]) * S2;
    } else if (d < 4) {
        float s = 0.f;
        #pragma unroll
        for (int k = 0; k < 128; ++k) s += pq[k][d];
        ws[128 + d] = s * S2;
    } else if (d == 4) {
        float s = 0.f;
        #pragma unroll
        for (int k = 0; k < 128; ++k) s += pc[k];
        ws[132] = s * S2;
    }
}

__global__ __launch_bounds__(256, 8) void ap_main(
    const float* __restrict__ x, const float* __restrict__ pos,
    const int* __restrict__ mask,
    const float* __restrict__ Wv, const float* __restrict__ bv,
    const float* __restrict__ ws, float* __restrict__ out)
{
    __shared__ float spos[520];                    // padded: idx = s + (s>>7)
    __shared__ float sacc[8][DIM];
    __shared__ float sm[8], sl[8];
    __shared__ alignas(16) float t[DIM];

    const int b   = blockIdx.x;
    const int tid = threadIdx.x;
    const int l   = tid & 63;
    const int w   = tid >> 6;         // wave 0..3, owns rows [128w, 128w+128)
    const int h   = (tid >> 5) & 1;   // half: even(0)/odd(1) rows of the wave
    const int c   = tid & 31;         // column group (4 floats)
    const int st  = tid >> 5;         // merge state 0..7

    // ---- issue first 8 x-loads immediately (hide spos phase under them) ----
    const float4* xw = (const float4*)(x + (size_t)b * SEQ * DIM) + w * 4096;
    float4 v0 = xw[0 * 64 + l];
    float4 v1 = xw[1 * 64 + l];
    float4 v2 = xw[2 * 64 + l];
    float4 v3 = xw[3 * 64 + l];
    float4 v4 = xw[4 * 64 + l];
    float4 v5 = xw[5 * 64 + l];
    float4 v6 = xw[6 * 64 + l];
    float4 v7 = xw[7 * 64 + l];

    const float4 qk4 = ((const float4*)ws)[c];
    const float qp0 = ws[128], qp1 = ws[129], qp2 = ws[130], qp3 = ws[131];
    const float c0  = ws[132];

    // positional score (+c0), exp2-prescaled, masked; bank-conflict-padded
    #pragma unroll
    for (int s = tid; s < SEQ; s += 256) {
        float4 p4 = ((const float4*)pos)[(size_t)b * SEQ + s];
        float sc = fmaf(qp0, p4.x, fmaf(qp1, p4.y, fmaf(qp2, p4.z, fmaf(qp3, p4.w, c0))));
        if (mask[(size_t)b * SEQ + s] == 0) sc = -1e30f;
        spos[s + (s >> 7)] = sc;
    }
    __syncthreads();

    const int sp0 = w * 129 + h;      // padded spos index of row (128w + h)

    float m = -INFINITY, den = 0.f;
    float ax = 0.f, ay = 0.f, az = 0.f, aw = 0.f;

#define PROC(V, J)                                                          \
    {                                                                       \
        float r = (V).x * qk4.x;                                            \
        r = fmaf((V).y, qk4.y, r);                                          \
        r = fmaf((V).z, qk4.z, r);                                          \
        r = fmaf((V).w, qk4.w, r);                                          \
        r = dpp_add<0x121>(r);                                              \
        r = dpp_add<0x122>(r);                                              \
        r = dpp_add<0x124>(r);                                              \
        r = dpp_add<0x128>(r);                                              \
        r += __shfl_xor(r, 16);                                             \
        float sc = r + spos[sp0 + 2 * (J)];                                 \
        float dd = sc - m;                                                  \
        if (__builtin_expect(dd > 8.0f, 0)) {                               \
            float f = __builtin_amdgcn_exp2f(-dd);                          \
            den = fmaf(den, f, 1.0f);                                       \
            ax = fmaf(ax, f, (V).x); ay = fmaf(ay, f, (V).y);               \
            az = fmaf(az, f, (V).z); aw = fmaf(aw, f, (V).w);               \
            m = sc;                                                         \
        } else {                                                            \
            float p = __builtin_amdgcn_exp2f(dd);                           \
            den += p;                                                       \
            ax = fmaf(p, (V).x, ax); ay = fmaf(p, (V).y, ay);               \
            az = fmaf(p, (V).z, az); aw = fmaf(p, (V).w, aw);               \
        }                                                                   \
    }

    // ---- 8-deep rotating pipeline; exactly 8 chunks x 8 = 64 iterations ----
#define STEP(V, J)                                                          \
    {                                                                       \
        PROC(V, J);                                                         \
        if ((J) + 8 < 64) V = xw[(((J) + 8) * 64) + l];                     \
    }

    #pragma unroll
    for (int ch = 0; ch < 8; ++ch) {
        const int base = 8 * ch;
        STEP(v0, base + 0);
        STEP(v1, base + 1);
        STEP(v2, base + 2);
        STEP(v3, base + 3);
        STEP(v4, base + 4);
        STEP(v5, base + 5);
        STEP(v6, base + 6);
        STEP(v7, base + 7);
    }
#undef STEP
#undef PROC

    // ---- merge the 8 states ----
    if (c == 0) { sm[st] = m; sl[st] = den; }
    __syncthreads();
    float gm = -INFINITY;
    #pragma unroll
    for (int k = 0; k < 8; ++k) gm = fmaxf(gm, sm[k]);
    float f = __builtin_amdgcn_exp2f(m - gm);
    sacc[st][4 * c + 0] = ax * f;
    sacc[st][4 * c + 1] = ay * f;
    sacc[st][4 * c + 2] = az * f;
    sacc[st][4 * c + 3] = aw * f;
    float gl = 0.f;
    #pragma unroll
    for (int k = 0; k < 8; ++k) gl += sl[k] * __builtin_amdgcn_exp2f(sm[k] - gm);
    __syncthreads();

    if (tid < DIM) {
        float s0 = 0.f;
        #pragma unroll
        for (int k = 0; k < 8; ++k) s0 += sacc[k][tid];
        t[tid] = s0;
    }
    __syncthreads();

    // ---- epilogue: pooled[b,k] = bv[k] + (Wv[k,:] . t) / gl ----
    if (tid < DIM) {
        const float4* wv4 = (const float4*)(Wv + tid * DIM);
        const float4* t4  = (const float4*)t;
        float sum = 0.f;
        #pragma unroll
        for (int j = 0; j < 32; ++j) {
            float4 wv = wv4[j];
            float4 tv = t4[j];
            sum += wv.x * tv.x + wv.y * tv.y + wv.z * tv.z + wv.w * tv.w;
        }
        out[(size_t)b * DIM + tid] = bv[tid] + sum / gl;
    }
}

extern "C" void kernel_launch(void* const* d_in, const int* in_sizes, int n_in,
                              void* d_out, int out_size, void* d_ws, size_t ws_size,
                              hipStream_t stream) {
    const float* x     = (const float*)d_in[0];
    const float* pos   = (const float*)d_in[1];
    const int*   mask  = (const int*)d_in[2];     // bool -> int32 per harness convention
    const float* query = (const float*)d_in[3];
    const float* Wk    = (const float*)d_in[4];
    const float* bk    = (const float*)d_in[5];
    const float* Wv    = (const float*)d_in[6];
    const float* bv    = (const float*)d_in[7];
    const float* Wp    = (const float*)d_in[8];
    const float* bp    = (const float*)d_in[9];
    float* out = (float*)d_out;
    float* ws  = (float*)d_ws;

    ap_prep<<<1, 256, 0, stream>>>(query, Wk, bk, Wp, bp, ws);
    ap_main<<<BATCH, 256, 0, stream>>>(x, pos, mask, Wv, bv, ws, out);
}